// Round 3
// baseline (3070.668 us; speedup 1.0000x reference)
//
#include <hip/hip_runtime.h>

#define NN 20000      // nodes
#define NE 160000     // edges per edge set
#define NL 20         // EGNN layer calls (4*DEPTH)

typedef float f32x4 __attribute__((ext_vector_type(4)));
typedef __bf16 bf16x8 __attribute__((ext_vector_type(8)));

__device__ __forceinline__ float silu_f(float v) {
  return v / (1.f + __expf(-v));
}

// ---------------------------------------------------------------------------
// Pack fp32 weight matrix [L][K][128] into MFMA-B-fragment order:
// out[((layer*ktn + kt)*8 + nt)*64 + lane][8], elem j = W[kt*32+(lane>>4)*8+j][nt*16+(lane&15)]
// ---------------------------------------------------------------------------
__global__ void pack_weights(const float* __restrict__ W, __bf16* __restrict__ out,
                             const int K, const int lstride, const int total) {
  const int idx = blockIdx.x * 256 + threadIdx.x;
  if (idx >= total) return;
  const int lane = idx & 63;
  const int nt = (idx >> 6) & 7;
  const int ktn = K >> 5;
  const int kt = (idx >> 9) % ktn;
  const int layer = (idx >> 9) / ktn;
  const int col = nt * 16 + (lane & 15);
  const int kb = kt * 32 + (lane >> 4) * 8;
  const float* src = W + (size_t)layer * lstride;
  __bf16* o = out + (size_t)idx * 8;
#pragma unroll
  for (int j = 0; j < 8; ++j) o[j] = (__bf16)src[(kb + j) * 128 + col];
}

// ---------------------------------------------------------------------------
__global__ void embed_kernel(const float* __restrict__ x, const float* __restrict__ embW,
                             const float* __restrict__ embB,
                             float* __restrict__ h, float* __restrict__ h0,
                             __bf16* __restrict__ hbf) {
  const int idx = blockIdx.x * 256 + threadIdx.x;   // grid sized exactly NN*128/256
  const int n = idx >> 7, d = idx & 127;
  const float v = x[n] * embW[d] + embB[d];
  h[idx] = v;
  h0[idx] = v;
  hbf[idx] = (__bf16)v;
}

// ---------------------------------------------------------------------------
// CSR build: histogram of dst, exclusive scan, ordered edge list.
// ---------------------------------------------------------------------------
__global__ void hist_kernel(const int* __restrict__ ei, int* __restrict__ deg) {
  const int e = blockIdx.x * 256 + threadIdx.x;   // grid exactly NE/256
  atomicAdd(&deg[ei[NE + e]], 1);
}

__global__ void scan_kernel(const int* __restrict__ deg, int* __restrict__ rowstart) {
  // one block (1024 thr) per edge set; exclusive scan of deg[r][0..NN)
  __shared__ int part[1024];
  const int r = blockIdx.x, t = threadIdx.x;
  const int* d = deg + (size_t)r * NN;
  int* rs = rowstart + (size_t)r * NN;
  int loc[20];
  int cnt = 0;
#pragma unroll
  for (int j = 0; j < 20; ++j) {
    const int i = t * 20 + j;
    const int v = (i < NN) ? d[i] : 0;
    loc[j] = cnt; cnt += v;
  }
  part[t] = cnt;
  __syncthreads();
  for (int off = 1; off < 1024; off <<= 1) {
    const int v = (t >= off) ? part[t - off] : 0;
    __syncthreads();
    part[t] += v;
    __syncthreads();
  }
  const int excl = (t == 0) ? 0 : part[t - 1];
#pragma unroll
  for (int j = 0; j < 20; ++j) {
    const int i = t * 20 + j;
    if (i < NN) rs[i] = excl + loc[j];
  }
}

__global__ void fill_kernel(const int* __restrict__ ei, const int* __restrict__ rowstart,
                            int* __restrict__ cursor, int* __restrict__ eord) {
  const int e = blockIdx.x * 256 + threadIdx.x;
  const int d = ei[NE + e];
  const int p = atomicAdd(&cursor[d], 1);
  eord[rowstart[d] + p] = e;
}

// ---------------------------------------------------------------------------
// Fused edge-message kernel: wave-independent, 32 edges/wave, NO atomics.
// Writes the 128-dim message per edge to msg[e] (bf16) via T1 repack.
// ---------------------------------------------------------------------------
__global__ __launch_bounds__(256, 4) void edge_msg_kernel(
    const __bf16* __restrict__ hbf, const float* __restrict__ pos,
    const int* __restrict__ ei, __bf16* __restrict__ msg,
    const __bf16* __restrict__ w1p, const __bf16* __restrict__ w2p,
    const float* __restrict__ w1last,
    const float* __restrict__ bm1, const float* __restrict__ gm1, const float* __restrict__ sm1,
    const float* __restrict__ bm2, const float* __restrict__ gm2, const float* __restrict__ sm2) {
  __shared__ __bf16 T1s[4][32 * 128];   // 32 KB, wave-private slices
  const int t = threadIdx.x, w = t >> 6, l = t & 63;
  const int lr = l & 15, lg = l >> 4;
  const int e0 = blockIdx.x * 128 + w * 32;
  char* T1 = (char*)T1s[w];

  const int es0 = ei[e0 + lr],      ed0 = ei[NE + e0 + lr];
  const int es1 = ei[e0 + 16 + lr], ed1 = ei[NE + e0 + 16 + lr];
  const int hi = lg & 1;
  const int eso = hi ? es1 : es0;
  const int edo = hi ? ed1 : ed0;
  const float dx = pos[edo * 3 + 0] - pos[eso * 3 + 0];
  const float dy = pos[edo * 3 + 1] - pos[eso * 3 + 1];
  const float dz = pos[edo * 3 + 2] - pos[eso * 3 + 2];
  const float dist_own = sqrtf(dx * dx + dy * dy + dz * dz);

  // acc init = dist*Wm1[256] + bm1 ; C layout: row = mt*16 + lg*4 + r, col = nt*16 + lr
  f32x4 acc[2][8];
  {
    float drow[2][4];
#pragma unroll
    for (int mt = 0; mt < 2; ++mt)
#pragma unroll
      for (int r = 0; r < 4; ++r)
        drow[mt][r] = __shfl(dist_own, mt * 16 + lg * 4 + r);
#pragma unroll
    for (int nt = 0; nt < 8; ++nt) {
      const float wl = w1last[nt * 16 + lr], bb = bm1[nt * 16 + lr];
#pragma unroll
      for (int mt = 0; mt < 2; ++mt)
#pragma unroll
        for (int r = 0; r < 4; ++r)
          acc[mt][nt][r] = drow[mt][r] * wl + bb;
    }
  }
  // GEMM1: [32 x 256] @ [256 x 128], A gathered from global hbf
#pragma unroll
  for (int kt = 0; kt < 8; ++kt) {
    const int koff = (kt & 3) * 32 + lg * 8;
    const int n0 = (kt < 4) ? ed0 : es0;
    const int n1 = (kt < 4) ? ed1 : es1;
    const bf16x8 a0 = *(const bf16x8*)(hbf + (size_t)n0 * 128 + koff);
    const bf16x8 a1 = *(const bf16x8*)(hbf + (size_t)n1 * 128 + koff);
#pragma unroll
    for (int nt = 0; nt < 8; ++nt) {
      const bf16x8 b = *(const bf16x8*)(w1p + ((size_t)((kt * 8 + nt) * 64 + l)) * 8);
      acc[0][nt] = __builtin_amdgcn_mfma_f32_16x16x32_bf16(a0, b, acc[0][nt], 0, 0, 0);
      acc[1][nt] = __builtin_amdgcn_mfma_f32_16x16x32_bf16(a1, b, acc[1][nt], 0, 0, 0);
    }
  }
  // LN1 + SiLU -> T1
  {
    float g1c[8], s1c[8];
#pragma unroll
    for (int nt = 0; nt < 8; ++nt) { g1c[nt] = gm1[nt * 16 + lr]; s1c[nt] = sm1[nt * 16 + lr]; }
#pragma unroll
    for (int mt = 0; mt < 2; ++mt)
#pragma unroll
      for (int r = 0; r < 4; ++r) {
        float s = 0.f, q = 0.f;
#pragma unroll
        for (int nt = 0; nt < 8; ++nt) { const float v = acc[mt][nt][r]; s += v; q += v * v; }
#pragma unroll
        for (int m = 1; m < 16; m <<= 1) { s += __shfl_xor(s, m); q += __shfl_xor(q, m); }
        const float mu = s * 0.0078125f;
        const float rstd = rsqrtf(q * 0.0078125f - mu * mu + 1e-5f);
        const int row = mt * 16 + lg * 4 + r;
#pragma unroll
        for (int nt = 0; nt < 8; ++nt) {
          float v = (acc[mt][nt][r] - mu) * rstd * g1c[nt] + s1c[nt];
          v = silu_f(v);
          const int col = nt * 16 + lr;
          *(__bf16*)(T1 + ((row * 256 + col * 2) ^ ((row & 7) << 4))) = (__bf16)v;
        }
      }
  }
  // GEMM2: [32 x 128] @ [128 x 128]
  f32x4 acc2[2][8];
#pragma unroll
  for (int nt = 0; nt < 8; ++nt) {
    const float bb = bm2[nt * 16 + lr];
#pragma unroll
    for (int mt = 0; mt < 2; ++mt)
#pragma unroll
      for (int r = 0; r < 4; ++r) acc2[mt][nt][r] = bb;
  }
#pragma unroll
  for (int kt = 0; kt < 4; ++kt) {
    const bf16x8 a0 = *(const bf16x8*)(T1 + (((lr) * 256 + kt * 64 + lg * 16) ^ ((lr & 7) << 4)));
    const bf16x8 a1 = *(const bf16x8*)(T1 + (((16 + lr) * 256 + kt * 64 + lg * 16) ^ ((lr & 7) << 4)));
#pragma unroll
    for (int nt = 0; nt < 8; ++nt) {
      const bf16x8 b = *(const bf16x8*)(w2p + ((size_t)((kt * 8 + nt) * 64 + l)) * 8);
      acc2[0][nt] = __builtin_amdgcn_mfma_f32_16x16x32_bf16(a0, b, acc2[0][nt], 0, 0, 0);
      acc2[1][nt] = __builtin_amdgcn_mfma_f32_16x16x32_bf16(a1, b, acc2[1][nt], 0, 0, 0);
    }
  }
  // LN2 + SiLU -> T1 (reuse; all GEMM2 reads precede in program order) -> 16B stores
  {
    float g2c[8], s2c[8];
#pragma unroll
    for (int nt = 0; nt < 8; ++nt) { g2c[nt] = gm2[nt * 16 + lr]; s2c[nt] = sm2[nt * 16 + lr]; }
#pragma unroll
    for (int mt = 0; mt < 2; ++mt)
#pragma unroll
      for (int r = 0; r < 4; ++r) {
        float s = 0.f, q = 0.f;
#pragma unroll
        for (int nt = 0; nt < 8; ++nt) { const float v = acc2[mt][nt][r]; s += v; q += v * v; }
#pragma unroll
        for (int m = 1; m < 16; m <<= 1) { s += __shfl_xor(s, m); q += __shfl_xor(q, m); }
        const float mu = s * 0.0078125f;
        const float rstd = rsqrtf(q * 0.0078125f - mu * mu + 1e-5f);
        const int row = mt * 16 + lg * 4 + r;
#pragma unroll
        for (int nt = 0; nt < 8; ++nt) {
          float v = (acc2[mt][nt][r] - mu) * rstd * g2c[nt] + s2c[nt];
          v = silu_f(v);
          const int col = nt * 16 + lr;
          *(__bf16*)(T1 + ((row * 256 + col * 2) ^ ((row & 7) << 4))) = (__bf16)v;
        }
      }
    // coalesced msg store: lane handles row = l&31, half = l>>5
    const int row = l & 31, half = l >> 5;
#pragma unroll
    for (int j = 0; j < 8; ++j) {
      const uint4 v = *(const uint4*)(T1 + ((row * 256 + half * 128 + j * 16) ^ ((row & 7) << 4)));
      *(uint4*)(msg + (size_t)(e0 + row) * 128 + half * 64 + j * 8) = v;
    }
  }
}

// ---------------------------------------------------------------------------
// Fused CSR-gather aggregation + node-update MLP. 1 wave/block, 16 nodes/wave.
// agg never touches memory: summed in registers from msg rows.
// ---------------------------------------------------------------------------
__global__ __launch_bounds__(64) void agg_update_kernel(
    float* __restrict__ h, __bf16* __restrict__ hbf, float* __restrict__ h0, const int mode,
    const __bf16* __restrict__ msg, const int* __restrict__ rowstart,
    const int* __restrict__ deg, const int* __restrict__ eord,
    const __bf16* __restrict__ w1p, const __bf16* __restrict__ w2p,
    const float* __restrict__ bu1, const float* __restrict__ gu1, const float* __restrict__ su1,
    const float* __restrict__ bu2, const float* __restrict__ gu2, const float* __restrict__ su2) {
  __shared__ __bf16 T1s[16 * 128];   // 4 KB
  char* T1 = (char*)T1s;
  const int l = threadIdx.x, lr = l & 15, lg = l >> 4;
  const int n0 = blockIdx.x * 16;
  const int n = n0 + lr;
  const int valid = (n < NN);

  // gather-sum messages for node n (lanes with same lr share the walk)
  f32x4 agg[4][2];
#pragma unroll
  for (int kt = 0; kt < 4; ++kt) { agg[kt][0] = (f32x4)0.f; agg[kt][1] = (f32x4)0.f; }
  if (valid) {
    const int s = rowstart[n], dg = deg[n];
    for (int i = 0; i < dg; ++i) {
      const __bf16* mrow = msg + (size_t)eord[s + i] * 128 + lg * 8;
#pragma unroll
      for (int kt = 0; kt < 4; ++kt) {
        const bf16x8 mv = *(const bf16x8*)(mrow + kt * 32);
#pragma unroll
        for (int j = 0; j < 4; ++j) {
          agg[kt][0][j] += (float)mv[j];
          agg[kt][1][j] += (float)mv[j + 4];
        }
      }
    }
  }
  // A fragments: kt 0..3 from hbf (coalesced rows), kt 4..7 from agg registers
  const int nc = valid ? n : 0;
  bf16x8 ah[4], af[4];
#pragma unroll
  for (int kt = 0; kt < 4; ++kt) {
    ah[kt] = *(const bf16x8*)(hbf + (size_t)nc * 128 + kt * 32 + lg * 8);
#pragma unroll
    for (int j = 0; j < 4; ++j) {
      af[kt][j] = (__bf16)agg[kt][0][j];
      af[kt][j + 4] = (__bf16)agg[kt][1][j];
    }
  }
  // GEMM1: [16 x 256] @ [256 x 128]
  f32x4 acc[8];
#pragma unroll
  for (int nt = 0; nt < 8; ++nt) {
    const float bb = bu1[nt * 16 + lr];
#pragma unroll
    for (int r = 0; r < 4; ++r) acc[nt][r] = bb;
  }
#pragma unroll
  for (int kt = 0; kt < 8; ++kt) {
    const bf16x8 a = (kt < 4) ? ah[kt] : af[kt - 4];
#pragma unroll
    for (int nt = 0; nt < 8; ++nt) {
      const bf16x8 b = *(const bf16x8*)(w1p + ((size_t)((kt * 8 + nt) * 64 + l)) * 8);
      acc[nt] = __builtin_amdgcn_mfma_f32_16x16x32_bf16(a, b, acc[nt], 0, 0, 0);
    }
  }
  // LN1 + SiLU -> T1
  {
    float g1c[8], s1c[8];
#pragma unroll
    for (int nt = 0; nt < 8; ++nt) { g1c[nt] = gu1[nt * 16 + lr]; s1c[nt] = su1[nt * 16 + lr]; }
#pragma unroll
    for (int r = 0; r < 4; ++r) {
      float s = 0.f, q = 0.f;
#pragma unroll
      for (int nt = 0; nt < 8; ++nt) { const float v = acc[nt][r]; s += v; q += v * v; }
#pragma unroll
      for (int m = 1; m < 16; m <<= 1) { s += __shfl_xor(s, m); q += __shfl_xor(q, m); }
      const float mu = s * 0.0078125f;
      const float rstd = rsqrtf(q * 0.0078125f - mu * mu + 1e-5f);
      const int row = lg * 4 + r;
#pragma unroll
      for (int nt = 0; nt < 8; ++nt) {
        float v = (acc[nt][r] - mu) * rstd * g1c[nt] + s1c[nt];
        v = silu_f(v);
        const int col = nt * 16 + lr;
        *(__bf16*)(T1 + ((row * 256 + col * 2) ^ ((row & 7) << 4))) = (__bf16)v;
      }
    }
  }
  // GEMM2: [16 x 128] @ [128 x 128]
  f32x4 acc2[8];
#pragma unroll
  for (int nt = 0; nt < 8; ++nt) {
    const float bb = bu2[nt * 16 + lr];
#pragma unroll
    for (int r = 0; r < 4; ++r) acc2[nt][r] = bb;
  }
#pragma unroll
  for (int kt = 0; kt < 4; ++kt) {
    const bf16x8 a = *(const bf16x8*)(T1 + ((lr * 256 + kt * 64 + lg * 16) ^ ((lr & 7) << 4)));
#pragma unroll
    for (int nt = 0; nt < 8; ++nt) {
      const bf16x8 b = *(const bf16x8*)(w2p + ((size_t)((kt * 8 + nt) * 64 + l)) * 8);
      acc2[nt] = __builtin_amdgcn_mfma_f32_16x16x32_bf16(a, b, acc2[nt], 0, 0, 0);
    }
  }
  // LN2 + SiLU + store h/hbf (+ residual, h0)
  {
    float g2c[8], s2c[8];
#pragma unroll
    for (int nt = 0; nt < 8; ++nt) { g2c[nt] = gu2[nt * 16 + lr]; s2c[nt] = su2[nt * 16 + lr]; }
#pragma unroll
    for (int r = 0; r < 4; ++r) {
      float s = 0.f, q = 0.f;
#pragma unroll
      for (int nt = 0; nt < 8; ++nt) { const float v = acc2[nt][r]; s += v; q += v * v; }
#pragma unroll
      for (int m = 1; m < 16; m <<= 1) { s += __shfl_xor(s, m); q += __shfl_xor(q, m); }
      const float mu = s * 0.0078125f;
      const float rstd = rsqrtf(q * 0.0078125f - mu * mu + 1e-5f);
      const int row = lg * 4 + r;
      const int nn = n0 + row;
      if (nn < NN) {
#pragma unroll
        for (int nt = 0; nt < 8; ++nt) {
          const int col = nt * 16 + lr;
          float v = (acc2[nt][r] - mu) * rstd * g2c[nt] + s2c[nt];
          v = silu_f(v);
          if (mode) v += h0[(size_t)nn * 128 + col];
          h[(size_t)nn * 128 + col] = v;
          hbf[(size_t)nn * 128 + col] = (__bf16)v;
          if (mode) h0[(size_t)nn * 128 + col] = v;
        }
      }
    }
  }
}

// ---------------------------------------------------------------------------
__global__ void pool_kernel(const float* __restrict__ h, const int* __restrict__ bid,
                            float* __restrict__ pooled) {
  const int idx = blockIdx.x * 256 + threadIdx.x;   // grid sized exactly NN*128/256
  const int n = idx >> 7;
  atomicAdd(&pooled[bid[n] * 128 + (idx & 127)], h[idx]);
}

__global__ void head_kernel(const float* __restrict__ pooled,
                            const float* __restrict__ W1, const float* __restrict__ b1,
                            const float* __restrict__ W2, const float* __restrict__ b2,
                            float* __restrict__ out) {
  __shared__ float buf[2];
  const int b = blockIdx.x, t = threadIdx.x;
  float s = b1[t];
  for (int k = 0; k < 128; ++k) s += pooled[b * 128 + k] * W1[k * 128 + t];
  s = fmaxf(s, 0.f) * W2[t];
#pragma unroll
  for (int m = 32; m >= 1; m >>= 1) s += __shfl_down(s, m);
  if ((t & 63) == 0) buf[t >> 6] = s;
  __syncthreads();
  if (t == 0) out[b] = buf[0] + buf[1] + b2[0];
}

// ---------------------------------------------------------------------------
extern "C" void kernel_launch(void* const* d_in, const int* in_sizes, int n_in,
                              void* d_out, int out_size, void* d_ws, size_t ws_size,
                              hipStream_t stream) {
  const float* x   = (const float*)d_in[0];
  const float* pos = (const float*)d_in[1];
  const int* eis[4] = {(const int*)d_in[2], (const int*)d_in[3],
                       (const int*)d_in[4], (const int*)d_in[5]};
  const int* bid = (const int*)d_in[6];
  const float* embW = (const float*)d_in[7];
  const float* embB = (const float*)d_in[8];
  const float* Wm1 = (const float*)d_in[9];
  const float* bm1 = (const float*)d_in[10];
  const float* gm1 = (const float*)d_in[11];
  const float* sm1 = (const float*)d_in[12];
  const float* Wm2 = (const float*)d_in[13];
  const float* bm2 = (const float*)d_in[14];
  const float* gm2 = (const float*)d_in[15];
  const float* sm2 = (const float*)d_in[16];
  const float* Wu1 = (const float*)d_in[17];
  const float* bu1 = (const float*)d_in[18];
  const float* gu1 = (const float*)d_in[19];
  const float* su1 = (const float*)d_in[20];
  const float* Wu2 = (const float*)d_in[21];
  const float* bu2 = (const float*)d_in[22];
  const float* gu2 = (const float*)d_in[23];
  const float* su2 = (const float*)d_in[24];
  const float* pW1 = (const float*)d_in[25];
  const float* pb1 = (const float*)d_in[26];
  const float* pW2 = (const float*)d_in[27];
  const float* pb2 = (const float*)d_in[28];
  float* out = (float*)d_out;

  char* wp = (char*)d_ws;
  float* h = (float*)wp;      wp += (size_t)NN * 128 * 4;
  float* h0 = (float*)wp;     wp += (size_t)NN * 128 * 4;
  float* pooled = (float*)wp; wp += 16 * 128 * 4;
  __bf16* hbf = (__bf16*)wp;  wp += (size_t)NN * 128 * 2;
  __bf16* msg = (__bf16*)wp;  wp += (size_t)NE * 128 * 2;   // 41 MB per-layer message buffer
  __bf16* w1p = (__bf16*)wp;  wp += (size_t)NL * 32768 * 2;
  __bf16* w2p = (__bf16*)wp;  wp += (size_t)NL * 16384 * 2;
  __bf16* wu1p = (__bf16*)wp; wp += (size_t)NL * 32768 * 2;
  __bf16* wu2p = (__bf16*)wp; wp += (size_t)NL * 16384 * 2;
  int* deg = (int*)wp;        wp += (size_t)4 * NN * 4;
  int* cursor = (int*)wp;     wp += (size_t)4 * NN * 4;
  int* rowstart = (int*)wp;   wp += (size_t)4 * NN * 4;
  int* eord = (int*)wp;       wp += (size_t)4 * NE * 4;

  pack_weights<<<320, 256, 0, stream>>>(Wm1, w1p, 256, 257 * 128, NL * 8 * 8 * 64);
  pack_weights<<<160, 256, 0, stream>>>(Wm2, w2p, 128, 128 * 128, NL * 4 * 8 * 64);
  pack_weights<<<320, 256, 0, stream>>>(Wu1, wu1p, 256, 256 * 128, NL * 8 * 8 * 64);
  pack_weights<<<160, 256, 0, stream>>>(Wu2, wu2p, 128, 128 * 128, NL * 4 * 8 * 64);

  // CSR build (deg and cursor are adjacent -> one memset)
  hipMemsetAsync(deg, 0, (size_t)8 * NN * 4, stream);
  embed_kernel<<<(NN * 128) / 256, 256, 0, stream>>>(x, embW, embB, h, h0, hbf);
  for (int r = 0; r < 4; ++r)
    hist_kernel<<<NE / 256, 256, 0, stream>>>(eis[r], deg + (size_t)r * NN);
  scan_kernel<<<4, 1024, 0, stream>>>(deg, rowstart);
  for (int r = 0; r < 4; ++r)
    fill_kernel<<<NE / 256, 256, 0, stream>>>(eis[r], rowstart + (size_t)r * NN,
                                              cursor + (size_t)r * NN, eord + (size_t)r * NE);

  for (int layer = 0; layer < 5; ++layer) {
    for (int r = 0; r < 4; ++r) {
      const int i = layer * 4 + r;
      edge_msg_kernel<<<NE / 128, 256, 0, stream>>>(
          hbf, pos, eis[r], msg,
          w1p + (size_t)i * 32768, w2p + (size_t)i * 16384,
          Wm1 + (size_t)i * 257 * 128 + 256 * 128,
          bm1 + i * 128, gm1 + i * 128, sm1 + i * 128,
          bm2 + i * 128, gm2 + i * 128, sm2 + i * 128);
      agg_update_kernel<<<(NN + 15) / 16, 64, 0, stream>>>(
          h, hbf, h0, (r == 3) ? 1 : 0,
          msg, rowstart + (size_t)r * NN, deg + (size_t)r * NN, eord + (size_t)r * NE,
          wu1p + (size_t)i * 32768, wu2p + (size_t)i * 16384,
          bu1 + i * 128, gu1 + i * 128, su1 + i * 128,
          bu2 + i * 128, gu2 + i * 128, su2 + i * 128);
    }
  }

  hipMemsetAsync(pooled, 0, 16 * 128 * 4, stream);
  pool_kernel<<<(NN * 128) / 256, 256, 0, stream>>>(h, bid, pooled);
  head_kernel<<<16, 128, 0, stream>>>(pooled, pW1, pb1, pW2, pb2, out);
}

// Round 4
// 2019.863 us; speedup vs baseline: 1.5202x; 1.5202x over previous
//
#include <hip/hip_runtime.h>

#define NN 20000      // nodes
#define NE 160000     // edges per edge set
#define NL 20         // EGNN layer calls (4*DEPTH)

typedef float f32x4 __attribute__((ext_vector_type(4)));
typedef __bf16 bf16x8 __attribute__((ext_vector_type(8)));

__device__ __forceinline__ float silu_f(float v) {
  return v / (1.f + __expf(-v));
}

// ---------------------------------------------------------------------------
// Pack fp32 weight matrix [L][K][128] into MFMA-B-fragment order:
// out[((layer*ktn + kt)*8 + nt)*64 + lane][8], elem j = W[kt*32+(lane>>4)*8+j][nt*16+(lane&15)]
// ---------------------------------------------------------------------------
__global__ void pack_weights(const float* __restrict__ W, __bf16* __restrict__ out,
                             const int K, const int lstride, const int total) {
  const int idx = blockIdx.x * 256 + threadIdx.x;
  if (idx >= total) return;
  const int lane = idx & 63;
  const int nt = (idx >> 6) & 7;
  const int ktn = K >> 5;
  const int kt = (idx >> 9) % ktn;
  const int layer = (idx >> 9) / ktn;
  const int col = nt * 16 + (lane & 15);
  const int kb = kt * 32 + (lane >> 4) * 8;
  const float* src = W + (size_t)layer * lstride;
  __bf16* o = out + (size_t)idx * 8;
#pragma unroll
  for (int j = 0; j < 8; ++j) o[j] = (__bf16)src[(kb + j) * 128 + col];
}

// ---------------------------------------------------------------------------
__global__ void embed_kernel(const float* __restrict__ x, const float* __restrict__ embW,
                             const float* __restrict__ embB,
                             float* __restrict__ h, float* __restrict__ h0,
                             __bf16* __restrict__ hbf) {
  const int idx = blockIdx.x * 256 + threadIdx.x;   // grid sized exactly NN*128/256
  const int n = idx >> 7, d = idx & 127;
  const float v = x[n] * embW[d] + embB[d];
  h[idx] = v;
  h0[idx] = v;
  hbf[idx] = (__bf16)v;
}

// ---------------------------------------------------------------------------
// CSR build: histogram of dst, exclusive scan, ordered edge list.
// ---------------------------------------------------------------------------
__global__ void hist_kernel(const int* __restrict__ ei, int* __restrict__ deg) {
  const int e = blockIdx.x * 256 + threadIdx.x;   // grid exactly NE/256
  atomicAdd(&deg[ei[NE + e]], 1);
}

__global__ void scan_kernel(const int* __restrict__ deg, int* __restrict__ rowstart) {
  // one block (1024 thr) per edge set; exclusive scan of deg[r][0..NN)
  __shared__ int part[1024];
  const int r = blockIdx.x, t = threadIdx.x;
  const int* d = deg + (size_t)r * NN;
  int* rs = rowstart + (size_t)r * NN;
  int loc[20];
  int cnt = 0;
#pragma unroll
  for (int j = 0; j < 20; ++j) {
    const int i = t * 20 + j;
    const int v = (i < NN) ? d[i] : 0;
    loc[j] = cnt; cnt += v;
  }
  part[t] = cnt;
  __syncthreads();
  for (int off = 1; off < 1024; off <<= 1) {
    const int v = (t >= off) ? part[t - off] : 0;
    __syncthreads();
    part[t] += v;
    __syncthreads();
  }
  const int excl = (t == 0) ? 0 : part[t - 1];
#pragma unroll
  for (int j = 0; j < 20; ++j) {
    const int i = t * 20 + j;
    if (i < NN) rs[i] = excl + loc[j];
  }
}

__global__ void fill_kernel(const int* __restrict__ ei, const int* __restrict__ rowstart,
                            int* __restrict__ cursor, int* __restrict__ eord) {
  const int e = blockIdx.x * 256 + threadIdx.x;
  const int d = ei[NE + e];
  const int p = atomicAdd(&cursor[d], 1);
  eord[rowstart[d] + p] = e;
}

// ---------------------------------------------------------------------------
// Fused edge-message kernel, weights-in-LDS version.
// Block = 1024 threads (16 waves). W1(64KB)+W2(32KB) staged to LDS once, then
// each wave independently processes 16 edges (full 16-row MFMAs):
//   GEMM1 (K=256, A gathered from global hbf, B via ds_read) -> LN -> SiLU ->
//   GEMM2 (K=128) -> LN -> SiLU -> coalesced 1KB msg stores.
// Dynamic LDS = 96KB weights + 16 x 4KB per-wave T1 = 160KB (1 block/CU).
// ---------------------------------------------------------------------------
__global__ __launch_bounds__(1024, 4) void edge_msg_kernel(
    const __bf16* __restrict__ hbf, const float* __restrict__ pos,
    const int* __restrict__ ei, __bf16* __restrict__ msg,
    const __bf16* __restrict__ w1p, const __bf16* __restrict__ w2p,
    const float* __restrict__ w1last,
    const float* __restrict__ bm1, const float* __restrict__ gm1, const float* __restrict__ sm1,
    const float* __restrict__ bm2, const float* __restrict__ gm2, const float* __restrict__ sm2) {
  extern __shared__ char lds[];
  // stage packed weights (layer slice): W1 = 4096 uint4, W2 = 2048 uint4
  {
    const int t = threadIdx.x;
    uint4* d = (uint4*)lds;
    const uint4* s1 = (const uint4*)w1p;
#pragma unroll
    for (int j = 0; j < 4; ++j) d[t + j * 1024] = s1[t + j * 1024];
    const uint4* s2 = (const uint4*)w2p;
#pragma unroll
    for (int j = 0; j < 2; ++j) d[4096 + t + j * 1024] = s2[t + j * 1024];
  }
  __syncthreads();

  const int t = threadIdx.x, w = t >> 6, l = t & 63;
  const int lr = l & 15, lg = l >> 4;
  char* W1L = lds;                        // 64 KB
  char* W2L = lds + 65536;                // 32 KB
  char* T1  = lds + 98304 + w * 4096;     // 4 KB per wave

  const int e0 = blockIdx.x * 256 + w * 16;
  const int es = ei[e0 + lr], ed = ei[NE + e0 + lr];   // lane lr owns edge lr
  const float dx = pos[ed * 3 + 0] - pos[es * 3 + 0];
  const float dy = pos[ed * 3 + 1] - pos[es * 3 + 1];
  const float dz = pos[ed * 3 + 2] - pos[es * 3 + 2];
  const float dist = sqrtf(dx * dx + dy * dy + dz * dz);

  // acc init = dist*Wm1[256] + bm1; C layout: row(edge) = lg*4+r, col = nt*16+lr
  f32x4 acc[8];
  {
    float drow[4];
#pragma unroll
    for (int r = 0; r < 4; ++r) drow[r] = __shfl(dist, lg * 4 + r);
#pragma unroll
    for (int nt = 0; nt < 8; ++nt) {
      const float wl = w1last[nt * 16 + lr], bb = bm1[nt * 16 + lr];
#pragma unroll
      for (int r = 0; r < 4; ++r) acc[nt][r] = drow[r] * wl + bb;
    }
  }
  // GEMM1: [16 x 256] @ [256 x 128]; A gathered from hbf, B from LDS
#pragma unroll
  for (int kt = 0; kt < 8; ++kt) {
    const int node = (kt < 4) ? ed : es;
    const bf16x8 a = *(const bf16x8*)(hbf + (size_t)node * 128 + (kt & 3) * 32 + lg * 8);
#pragma unroll
    for (int nt = 0; nt < 8; ++nt) {
      const bf16x8 b = *(const bf16x8*)(W1L + ((kt * 8 + nt) * 64 + l) * 16);
      acc[nt] = __builtin_amdgcn_mfma_f32_16x16x32_bf16(a, b, acc[nt], 0, 0, 0);
    }
  }
  // LN1 + SiLU -> T1
  {
    float g1c[8], s1c[8];
#pragma unroll
    for (int nt = 0; nt < 8; ++nt) { g1c[nt] = gm1[nt * 16 + lr]; s1c[nt] = sm1[nt * 16 + lr]; }
#pragma unroll
    for (int r = 0; r < 4; ++r) {
      float s = 0.f, q = 0.f;
#pragma unroll
      for (int nt = 0; nt < 8; ++nt) { const float v = acc[nt][r]; s += v; q += v * v; }
#pragma unroll
      for (int m = 1; m < 16; m <<= 1) { s += __shfl_xor(s, m); q += __shfl_xor(q, m); }
      const float mu = s * 0.0078125f;
      const float rstd = rsqrtf(q * 0.0078125f - mu * mu + 1e-5f);
      const int row = lg * 4 + r;
#pragma unroll
      for (int nt = 0; nt < 8; ++nt) {
        float v = (acc[nt][r] - mu) * rstd * g1c[nt] + s1c[nt];
        v = silu_f(v);
        *(__bf16*)(T1 + ((row * 256 + (nt * 16 + lr) * 2) ^ ((row & 7) << 4))) = (__bf16)v;
      }
    }
  }
  // GEMM2: [16 x 128] @ [128 x 128]
  f32x4 acc2[8];
#pragma unroll
  for (int nt = 0; nt < 8; ++nt) {
    const float bb = bm2[nt * 16 + lr];
#pragma unroll
    for (int r = 0; r < 4; ++r) acc2[nt][r] = bb;
  }
#pragma unroll
  for (int kt = 0; kt < 4; ++kt) {
    const bf16x8 a = *(const bf16x8*)(T1 + ((lr * 256 + kt * 64 + lg * 16) ^ ((lr & 7) << 4)));
#pragma unroll
    for (int nt = 0; nt < 8; ++nt) {
      const bf16x8 b = *(const bf16x8*)(W2L + ((kt * 8 + nt) * 64 + l) * 16);
      acc2[nt] = __builtin_amdgcn_mfma_f32_16x16x32_bf16(a, b, acc2[nt], 0, 0, 0);
    }
  }
  // LN2 + SiLU -> T1 (overwrite is safe: all GEMM2 reads precede in program order)
  {
    float g2c[8], s2c[8];
#pragma unroll
    for (int nt = 0; nt < 8; ++nt) { g2c[nt] = gm2[nt * 16 + lr]; s2c[nt] = sm2[nt * 16 + lr]; }
#pragma unroll
    for (int r = 0; r < 4; ++r) {
      float s = 0.f, q = 0.f;
#pragma unroll
      for (int nt = 0; nt < 8; ++nt) { const float v = acc2[nt][r]; s += v; q += v * v; }
#pragma unroll
      for (int m = 1; m < 16; m <<= 1) { s += __shfl_xor(s, m); q += __shfl_xor(q, m); }
      const float mu = s * 0.0078125f;
      const float rstd = rsqrtf(q * 0.0078125f - mu * mu + 1e-5f);
      const int row = lg * 4 + r;
#pragma unroll
      for (int nt = 0; nt < 8; ++nt) {
        float v = (acc2[nt][r] - mu) * rstd * g2c[nt] + s2c[nt];
        v = silu_f(v);
        *(__bf16*)(T1 + ((row * 256 + (nt * 16 + lr) * 2) ^ ((row & 7) << 4))) = (__bf16)v;
      }
    }
  }
  // coalesced msg store: 16 edges x 256B = 4KB as 4 x 1KB contiguous wave stores
  char* mbase = (char*)(msg + (size_t)e0 * 128);
#pragma unroll
  for (int j = 0; j < 4; ++j) {
    const int row = j * 4 + lg;
    const uint4 v = *(const uint4*)(T1 + ((row * 256 + lr * 16) ^ ((row & 7) << 4)));
    *(uint4*)(mbase + j * 1024 + l * 16) = v;
  }
}

// ---------------------------------------------------------------------------
// Fused CSR-gather aggregation + node-update MLP. 1 wave/block, 16 nodes/wave.
// agg never touches memory: summed in registers from msg rows.
// ---------------------------------------------------------------------------
__global__ __launch_bounds__(64) void agg_update_kernel(
    float* __restrict__ h, __bf16* __restrict__ hbf, float* __restrict__ h0, const int mode,
    const __bf16* __restrict__ msg, const int* __restrict__ rowstart,
    const int* __restrict__ deg, const int* __restrict__ eord,
    const __bf16* __restrict__ w1p, const __bf16* __restrict__ w2p,
    const float* __restrict__ bu1, const float* __restrict__ gu1, const float* __restrict__ su1,
    const float* __restrict__ bu2, const float* __restrict__ gu2, const float* __restrict__ su2) {
  __shared__ __bf16 T1s[16 * 128];   // 4 KB
  char* T1 = (char*)T1s;
  const int l = threadIdx.x, lr = l & 15, lg = l >> 4;
  const int n0 = blockIdx.x * 16;
  const int n = n0 + lr;
  const int valid = (n < NN);

  // gather-sum messages for node n (lanes with same lr share the walk)
  f32x4 agg[4][2];
#pragma unroll
  for (int kt = 0; kt < 4; ++kt) { agg[kt][0] = (f32x4)0.f; agg[kt][1] = (f32x4)0.f; }
  if (valid) {
    const int s = rowstart[n], dg = deg[n];
    for (int i = 0; i < dg; ++i) {
      const __bf16* mrow = msg + (size_t)eord[s + i] * 128 + lg * 8;
#pragma unroll
      for (int kt = 0; kt < 4; ++kt) {
        const bf16x8 mv = *(const bf16x8*)(mrow + kt * 32);
#pragma unroll
        for (int j = 0; j < 4; ++j) {
          agg[kt][0][j] += (float)mv[j];
          agg[kt][1][j] += (float)mv[j + 4];
        }
      }
    }
  }
  // A fragments: kt 0..3 from hbf (coalesced rows), kt 4..7 from agg registers
  const int nc = valid ? n : 0;
  bf16x8 ah[4], af[4];
#pragma unroll
  for (int kt = 0; kt < 4; ++kt) {
    ah[kt] = *(const bf16x8*)(hbf + (size_t)nc * 128 + kt * 32 + lg * 8);
#pragma unroll
    for (int j = 0; j < 4; ++j) {
      af[kt][j] = (__bf16)agg[kt][0][j];
      af[kt][j + 4] = (__bf16)agg[kt][1][j];
    }
  }
  // GEMM1: [16 x 256] @ [256 x 128]
  f32x4 acc[8];
#pragma unroll
  for (int nt = 0; nt < 8; ++nt) {
    const float bb = bu1[nt * 16 + lr];
#pragma unroll
    for (int r = 0; r < 4; ++r) acc[nt][r] = bb;
  }
#pragma unroll
  for (int kt = 0; kt < 8; ++kt) {
    const bf16x8 a = (kt < 4) ? ah[kt] : af[kt - 4];
#pragma unroll
    for (int nt = 0; nt < 8; ++nt) {
      const bf16x8 b = *(const bf16x8*)(w1p + ((size_t)((kt * 8 + nt) * 64 + l)) * 8);
      acc[nt] = __builtin_amdgcn_mfma_f32_16x16x32_bf16(a, b, acc[nt], 0, 0, 0);
    }
  }
  // LN1 + SiLU -> T1
  {
    float g1c[8], s1c[8];
#pragma unroll
    for (int nt = 0; nt < 8; ++nt) { g1c[nt] = gu1[nt * 16 + lr]; s1c[nt] = su1[nt * 16 + lr]; }
#pragma unroll
    for (int r = 0; r < 4; ++r) {
      float s = 0.f, q = 0.f;
#pragma unroll
      for (int nt = 0; nt < 8; ++nt) { const float v = acc[nt][r]; s += v; q += v * v; }
#pragma unroll
      for (int m = 1; m < 16; m <<= 1) { s += __shfl_xor(s, m); q += __shfl_xor(q, m); }
      const float mu = s * 0.0078125f;
      const float rstd = rsqrtf(q * 0.0078125f - mu * mu + 1e-5f);
      const int row = lg * 4 + r;
#pragma unroll
      for (int nt = 0; nt < 8; ++nt) {
        float v = (acc[nt][r] - mu) * rstd * g1c[nt] + s1c[nt];
        v = silu_f(v);
        const int col = nt * 16 + lr;
        *(__bf16*)(T1 + ((row * 256 + col * 2) ^ ((row & 7) << 4))) = (__bf16)v;
      }
    }
  }
  // GEMM2: [16 x 128] @ [128 x 128]
  f32x4 acc2[8];
#pragma unroll
  for (int nt = 0; nt < 8; ++nt) {
    const float bb = bu2[nt * 16 + lr];
#pragma unroll
    for (int r = 0; r < 4; ++r) acc2[nt][r] = bb;
  }
#pragma unroll
  for (int kt = 0; kt < 4; ++kt) {
    const bf16x8 a = *(const bf16x8*)(T1 + ((lr * 256 + kt * 64 + lg * 16) ^ ((lr & 7) << 4)));
#pragma unroll
    for (int nt = 0; nt < 8; ++nt) {
      const bf16x8 b = *(const bf16x8*)(w2p + ((size_t)((kt * 8 + nt) * 64 + l)) * 8);
      acc2[nt] = __builtin_amdgcn_mfma_f32_16x16x32_bf16(a, b, acc2[nt], 0, 0, 0);
    }
  }
  // LN2 + SiLU + store h/hbf (+ residual, h0)
  {
    float g2c[8], s2c[8];
#pragma unroll
    for (int nt = 0; nt < 8; ++nt) { g2c[nt] = gu2[nt * 16 + lr]; s2c[nt] = su2[nt * 16 + lr]; }
#pragma unroll
    for (int r = 0; r < 4; ++r) {
      float s = 0.f, q = 0.f;
#pragma unroll
      for (int nt = 0; nt < 8; ++nt) { const float v = acc2[nt][r]; s += v; q += v * v; }
#pragma unroll
      for (int m = 1; m < 16; m <<= 1) { s += __shfl_xor(s, m); q += __shfl_xor(q, m); }
      const float mu = s * 0.0078125f;
      const float rstd = rsqrtf(q * 0.0078125f - mu * mu + 1e-5f);
      const int row = lg * 4 + r;
      const int nn = n0 + row;
      if (nn < NN) {
#pragma unroll
        for (int nt = 0; nt < 8; ++nt) {
          const int col = nt * 16 + lr;
          float v = (acc2[nt][r] - mu) * rstd * g2c[nt] + s2c[nt];
          v = silu_f(v);
          if (mode) v += h0[(size_t)nn * 128 + col];
          h[(size_t)nn * 128 + col] = v;
          hbf[(size_t)nn * 128 + col] = (__bf16)v;
          if (mode) h0[(size_t)nn * 128 + col] = v;
        }
      }
    }
  }
}

// ---------------------------------------------------------------------------
__global__ void pool_kernel(const float* __restrict__ h, const int* __restrict__ bid,
                            float* __restrict__ pooled) {
  const int idx = blockIdx.x * 256 + threadIdx.x;   // grid sized exactly NN*128/256
  const int n = idx >> 7;
  atomicAdd(&pooled[bid[n] * 128 + (idx & 127)], h[idx]);
}

__global__ void head_kernel(const float* __restrict__ pooled,
                            const float* __restrict__ W1, const float* __restrict__ b1,
                            const float* __restrict__ W2, const float* __restrict__ b2,
                            float* __restrict__ out) {
  __shared__ float buf[2];
  const int b = blockIdx.x, t = threadIdx.x;
  float s = b1[t];
  for (int k = 0; k < 128; ++k) s += pooled[b * 128 + k] * W1[k * 128 + t];
  s = fmaxf(s, 0.f) * W2[t];
#pragma unroll
  for (int m = 32; m >= 1; m >>= 1) s += __shfl_down(s, m);
  if ((t & 63) == 0) buf[t >> 6] = s;
  __syncthreads();
  if (t == 0) out[b] = buf[0] + buf[1] + b2[0];
}

// ---------------------------------------------------------------------------
extern "C" void kernel_launch(void* const* d_in, const int* in_sizes, int n_in,
                              void* d_out, int out_size, void* d_ws, size_t ws_size,
                              hipStream_t stream) {
  const float* x   = (const float*)d_in[0];
  const float* pos = (const float*)d_in[1];
  const int* eis[4] = {(const int*)d_in[2], (const int*)d_in[3],
                       (const int*)d_in[4], (const int*)d_in[5]};
  const int* bid = (const int*)d_in[6];
  const float* embW = (const float*)d_in[7];
  const float* embB = (const float*)d_in[8];
  const float* Wm1 = (const float*)d_in[9];
  const float* bm1 = (const float*)d_in[10];
  const float* gm1 = (const float*)d_in[11];
  const float* sm1 = (const float*)d_in[12];
  const float* Wm2 = (const float*)d_in[13];
  const float* bm2 = (const float*)d_in[14];
  const float* gm2 = (const float*)d_in[15];
  const float* sm2 = (const float*)d_in[16];
  const float* Wu1 = (const float*)d_in[17];
  const float* bu1 = (const float*)d_in[18];
  const float* gu1 = (const float*)d_in[19];
  const float* su1 = (const float*)d_in[20];
  const float* Wu2 = (const float*)d_in[21];
  const float* bu2 = (const float*)d_in[22];
  const float* gu2 = (const float*)d_in[23];
  const float* su2 = (const float*)d_in[24];
  const float* pW1 = (const float*)d_in[25];
  const float* pb1 = (const float*)d_in[26];
  const float* pW2 = (const float*)d_in[27];
  const float* pb2 = (const float*)d_in[28];
  float* out = (float*)d_out;

  char* wp = (char*)d_ws;
  float* h = (float*)wp;      wp += (size_t)NN * 128 * 4;
  float* h0 = (float*)wp;     wp += (size_t)NN * 128 * 4;
  float* pooled = (float*)wp; wp += 16 * 128 * 4;
  __bf16* hbf = (__bf16*)wp;  wp += (size_t)NN * 128 * 2;
  __bf16* msg = (__bf16*)wp;  wp += (size_t)NE * 128 * 2;   // 41 MB per-layer message buffer
  __bf16* w1p = (__bf16*)wp;  wp += (size_t)NL * 32768 * 2;
  __bf16* w2p = (__bf16*)wp;  wp += (size_t)NL * 16384 * 2;
  __bf16* wu1p = (__bf16*)wp; wp += (size_t)NL * 32768 * 2;
  __bf16* wu2p = (__bf16*)wp; wp += (size_t)NL * 16384 * 2;
  int* deg = (int*)wp;        wp += (size_t)4 * NN * 4;
  int* cursor = (int*)wp;     wp += (size_t)4 * NN * 4;
  int* rowstart = (int*)wp;   wp += (size_t)4 * NN * 4;
  int* eord = (int*)wp;       wp += (size_t)4 * NE * 4;

  // allow 160KB dynamic LDS for the edge kernel (host-side, capture-safe)
  static int lds_attr_set = 0;
  if (!lds_attr_set) {
    hipFuncSetAttribute((const void*)edge_msg_kernel,
                        hipFuncAttributeMaxDynamicSharedMemorySize, 163840);
    lds_attr_set = 1;
  }

  pack_weights<<<320, 256, 0, stream>>>(Wm1, w1p, 256, 257 * 128, NL * 8 * 8 * 64);
  pack_weights<<<160, 256, 0, stream>>>(Wm2, w2p, 128, 128 * 128, NL * 4 * 8 * 64);
  pack_weights<<<320, 256, 0, stream>>>(Wu1, wu1p, 256, 256 * 128, NL * 8 * 8 * 64);
  pack_weights<<<160, 256, 0, stream>>>(Wu2, wu2p, 128, 128 * 128, NL * 4 * 8 * 64);

  // CSR build (deg and cursor are adjacent -> one memset)
  hipMemsetAsync(deg, 0, (size_t)8 * NN * 4, stream);
  embed_kernel<<<(NN * 128) / 256, 256, 0, stream>>>(x, embW, embB, h, h0, hbf);
  for (int r = 0; r < 4; ++r)
    hist_kernel<<<NE / 256, 256, 0, stream>>>(eis[r], deg + (size_t)r * NN);
  scan_kernel<<<4, 1024, 0, stream>>>(deg, rowstart);
  for (int r = 0; r < 4; ++r)
    fill_kernel<<<NE / 256, 256, 0, stream>>>(eis[r], rowstart + (size_t)r * NN,
                                              cursor + (size_t)r * NN, eord + (size_t)r * NE);

  for (int layer = 0; layer < 5; ++layer) {
    for (int r = 0; r < 4; ++r) {
      const int i = layer * 4 + r;
      edge_msg_kernel<<<NE / 256, 1024, 163840, stream>>>(
          hbf, pos, eis[r], msg,
          w1p + (size_t)i * 32768, w2p + (size_t)i * 16384,
          Wm1 + (size_t)i * 257 * 128 + 256 * 128,
          bm1 + i * 128, gm1 + i * 128, sm1 + i * 128,
          bm2 + i * 128, gm2 + i * 128, sm2 + i * 128);
      agg_update_kernel<<<(NN + 15) / 16, 64, 0, stream>>>(
          h, hbf, h0, (r == 3) ? 1 : 0,
          msg, rowstart + (size_t)r * NN, deg + (size_t)r * NN, eord + (size_t)r * NE,
          wu1p + (size_t)i * 32768, wu2p + (size_t)i * 16384,
          bu1 + i * 128, gu1 + i * 128, su1 + i * 128,
          bu2 + i * 128, gu2 + i * 128, su2 + i * 128);
    }
  }

  hipMemsetAsync(pooled, 0, 16 * 128 * 4, stream);
  pool_kernel<<<(NN * 128) / 256, 256, 0, stream>>>(h, bid, pooled);
  head_kernel<<<16, 128, 0, stream>>>(pooled, pW1, pb1, pW2, pb2, out);
}